// Round 1
// baseline (1520.896 us; speedup 1.0000x reference)
//
#include <hip/hip_runtime.h>

#define F 128
#define RB 64
#define VSTRIDE 132

// ---------------------------------------------------------------------------
// Kernel 1: edge scatter  e1[row] += val * x[col]
// One half-wave (32 lanes) per edge; each lane handles one float4 (4 feats).
// ---------------------------------------------------------------------------
__global__ __launch_bounds__(256) void scatter_k(
    const float* __restrict__ x, const float* __restrict__ edge_val,
    const int* __restrict__ erow, const int* __restrict__ ecol,
    float* e1, int E)
{
    const int gtid = blockIdx.x * blockDim.x + threadIdx.x;
    const int wid  = gtid >> 6;                      // global wave id
    const int nw   = (gridDim.x * blockDim.x) >> 6;  // total waves
    const int lane = threadIdx.x & 63;
    const int sub  = lane >> 5;                      // 0/1: which edge of pair
    const int l    = lane & 31;                      // float4 slot within row

    for (int e0 = wid * 2; e0 < E; e0 += nw * 2) {
        const int e = e0 + sub;
        if (e < E) {
            const int   r   = erow[e];
            const int   c   = ecol[e];
            const float val = edge_val[e];
            const float4 xv = ((const float4*)(x + (size_t)c * F))[l];
            float* dst = e1 + (size_t)r * F + l * 4;
            unsafeAtomicAdd(dst + 0, val * xv.x);
            unsafeAtomicAdd(dst + 1, val * xv.y);
            unsafeAtomicAdd(dst + 2, val * xv.z);
            unsafeAtomicAdd(dst + 3, val * xv.w);
        }
    }
}

// ---------------------------------------------------------------------------
// Kernel 2: out[i,:] = (x[i,:] - e1[i,:]*(diag+1)) @ W + bias
// In-place over e1 (== d_out): all reads of a block's rows happen before the
// __syncthreads, all writes after; blocks own disjoint rows.
// Block: 256 threads = 16(tx) x 16(ty); thread tile: 4 rows x 8 cols.
// ---------------------------------------------------------------------------
__global__ __launch_bounds__(256) void fused_k(
    const float* __restrict__ x, const float* e1,
    const float* __restrict__ W, const float* __restrict__ diag1,
    const float* __restrict__ bias, float* out, int N)
{
    __shared__ float vs[RB * VSTRIDE];
    const int t  = threadIdx.x;
    const int tx = t & 15;
    const int ty = t >> 4;
    const size_t row0 = (size_t)blockIdx.x * RB;

    // Phase 1: stage v = x - e1*(diag+1) for 64 rows into LDS
#pragma unroll
    for (int i = 0; i < 8; ++i) {
        const int idx = t + i * 256;       // 0..2047 float4 chunks
        const int r   = idx >> 5;          // row within tile
        const int k4  = idx & 31;          // float4 index within row
        const size_t row = row0 + r;
        float4 v = make_float4(0.f, 0.f, 0.f, 0.f);
        if (row < (size_t)N) {
            const float4 xv = ((const float4*)(x  + row * F))[k4];
            const float4 ev = ((const float4*)(e1 + row * F))[k4];
            const float4 dv = ((const float4*)diag1)[k4];
            v.x = xv.x - ev.x * (dv.x + 1.f);
            v.y = xv.y - ev.y * (dv.y + 1.f);
            v.z = xv.z - ev.z * (dv.z + 1.f);
            v.w = xv.w - ev.w * (dv.w + 1.f);
        }
        *(float4*)&vs[r * VSTRIDE + k4 * 4] = v;
    }
    __syncthreads();

    float acc[4][8];
#pragma unroll
    for (int rr = 0; rr < 4; ++rr)
#pragma unroll
        for (int c = 0; c < 8; ++c) acc[rr][c] = 0.f;

    for (int k = 0; k < F; k += 4) {
        float4 vf[4];
#pragma unroll
        for (int rr = 0; rr < 4; ++rr)
            vf[rr] = *(const float4*)&vs[(ty * 4 + rr) * VSTRIDE + k];
#pragma unroll
        for (int kk = 0; kk < 4; ++kk) {
            const float* wrow = W + (size_t)(k + kk) * F + tx * 8;
            const float4 wa = *(const float4*)(wrow);
            const float4 wb = *(const float4*)(wrow + 4);
#pragma unroll
            for (int rr = 0; rr < 4; ++rr) {
                const float vk = ((const float*)&vf[rr])[kk];
                acc[rr][0] = fmaf(vk, wa.x, acc[rr][0]);
                acc[rr][1] = fmaf(vk, wa.y, acc[rr][1]);
                acc[rr][2] = fmaf(vk, wa.z, acc[rr][2]);
                acc[rr][3] = fmaf(vk, wa.w, acc[rr][3]);
                acc[rr][4] = fmaf(vk, wb.x, acc[rr][4]);
                acc[rr][5] = fmaf(vk, wb.y, acc[rr][5]);
                acc[rr][6] = fmaf(vk, wb.z, acc[rr][6]);
                acc[rr][7] = fmaf(vk, wb.w, acc[rr][7]);
            }
        }
    }

    const float4 b0 = ((const float4*)bias)[tx * 2];
    const float4 b1 = ((const float4*)bias)[tx * 2 + 1];
#pragma unroll
    for (int rr = 0; rr < 4; ++rr) {
        const size_t row = row0 + ty * 4 + rr;
        if (row < (size_t)N) {
            float4 oa = make_float4(acc[rr][0] + b0.x, acc[rr][1] + b0.y,
                                    acc[rr][2] + b0.z, acc[rr][3] + b0.w);
            float4 ob = make_float4(acc[rr][4] + b1.x, acc[rr][5] + b1.y,
                                    acc[rr][6] + b1.z, acc[rr][7] + b1.w);
            ((float4*)(out + row * F))[tx * 2]     = oa;
            ((float4*)(out + row * F))[tx * 2 + 1] = ob;
        }
    }
}

extern "C" void kernel_launch(void* const* d_in, const int* in_sizes, int n_in,
                              void* d_out, int out_size, void* d_ws, size_t ws_size,
                              hipStream_t stream) {
    const float* x        = (const float*)d_in[0];
    const float* edge_val = (const float*)d_in[1];
    const float* weight   = (const float*)d_in[2];
    const float* diag1    = (const float*)d_in[3];
    const float* bias     = (const float*)d_in[4];
    const int*   erow     = (const int*)d_in[5];
    const int*   ecol     = (const int*)d_in[6];
    float* out = (float*)d_out;

    const int E = in_sizes[1];
    const int N = in_sizes[0] / F;

    // e1 accumulator lives in d_out (poisoned 0xAA each call -> zero it)
    hipMemsetAsync(out, 0, (size_t)N * F * sizeof(float), stream);

    // Scatter: 2048 blocks x 4 waves = 8192 waves (full occupancy), 2 edges/wave/iter
    scatter_k<<<2048, 256, 0, stream>>>(x, edge_val, erow, ecol, out, E);

    // Fused column-scale + GEMM + bias, in place over d_out
    const int gblocks = (N + RB - 1) / RB;
    fused_k<<<gblocks, 256, 0, stream>>>(x, out, weight, diag1, bias, out, N);
}

// Round 3
// 514.855 us; speedup vs baseline: 2.9540x; 2.9540x over previous
//
#include <hip/hip_runtime.h>

#define F 128
#define RB 64
#define VSTRIDE 132

// ---------------------------------------------------------------------------
// Fallback kernel (only if ws_size too small): edge scatter with f32 atomics
// ---------------------------------------------------------------------------
__global__ __launch_bounds__(256) void scatter_k(
    const float* __restrict__ x, const float* __restrict__ edge_val,
    const int* __restrict__ erow, const int* __restrict__ ecol,
    float* e1, int E)
{
    const int gtid = blockIdx.x * blockDim.x + threadIdx.x;
    const int wid  = gtid >> 6;
    const int nw   = (gridDim.x * blockDim.x) >> 6;
    const int lane = threadIdx.x & 63;
    const int sub  = lane >> 5;
    const int l    = lane & 31;

    for (int e0 = wid * 2; e0 < E; e0 += nw * 2) {
        const int e = e0 + sub;
        if (e < E) {
            const int   r   = erow[e];
            const int   c   = ecol[e];
            const float val = edge_val[e];
            const float4 xv = ((const float4*)(x + (size_t)c * F))[l];
            float* dst = e1 + (size_t)r * F + l * 4;
            unsafeAtomicAdd(dst + 0, val * xv.x);
            unsafeAtomicAdd(dst + 1, val * xv.y);
            unsafeAtomicAdd(dst + 2, val * xv.z);
            unsafeAtomicAdd(dst + 3, val * xv.w);
        }
    }
}

// ---------------------------------------------------------------------------
// CSR build: histogram of destination rows
// ---------------------------------------------------------------------------
__global__ __launch_bounds__(256) void hist_k(
    const int* __restrict__ erow, int* cnt, int E)
{
    int i = blockIdx.x * blockDim.x + threadIdx.x;
    if (i < E) atomicAdd(&cnt[erow[i]], 1);
}

// ---------------------------------------------------------------------------
// Single-block exclusive scan over N counts -> offs[0..N]
// 1024 threads; each owns a contiguous chunk; Hillis-Steele over chunk sums.
// ---------------------------------------------------------------------------
__global__ __launch_bounds__(1024) void scan_k(
    const int* __restrict__ cnt, int* offs, int N)
{
    __shared__ int sums[1024];
    const int t = threadIdx.x;
    const int chunk = (N + 1023) >> 10;
    const int begin = t * chunk;
    const int end   = min(begin + chunk, N);

    int s = 0;
    for (int i = begin; i < end; ++i) s += cnt[i];
    sums[t] = s;
    __syncthreads();
    for (int off = 1; off < 1024; off <<= 1) {
        int v = (t >= off) ? sums[t - off] : 0;
        __syncthreads();
        sums[t] += v;
        __syncthreads();
    }
    const int incl = sums[t];
    int run = incl - s;                 // exclusive prefix for this chunk
    for (int i = begin; i < end; ++i) { offs[i] = run; run += cnt[i]; }
    if (t == 1023) offs[N] = incl;      // grand total
}

// ---------------------------------------------------------------------------
// Reorder edges into row buckets: bcol/bval[pos], pos = offs[r] + cursor++
// ---------------------------------------------------------------------------
__global__ __launch_bounds__(256) void build_k(
    const int* __restrict__ erow, const int* __restrict__ ecol,
    const float* __restrict__ eval, const int* __restrict__ offs,
    int* cur, int* bcol, float* bval, int E)
{
    int i = blockIdx.x * blockDim.x + threadIdx.x;
    if (i < E) {
        const int r   = erow[i];
        const int pos = offs[r] + atomicAdd(&cur[r], 1);
        bcol[pos] = ecol[i];
        bval[pos] = eval[i];
    }
}

// ---------------------------------------------------------------------------
// Per-row gather-reduce: e1[r,:] = sum_{e in row r} val_e * x[col_e,:]
// One wave per row; lane handles float2 (64*2 = 128 feats). No atomics.
// ---------------------------------------------------------------------------
__global__ __launch_bounds__(256) void gather_k(
    const float* __restrict__ x, const int* __restrict__ bcol,
    const float* __restrict__ bval, const int* __restrict__ offs,
    float* __restrict__ e1, int N)
{
    const int wave = (blockIdx.x * blockDim.x + threadIdx.x) >> 6;
    const int lane = threadIdx.x & 63;
    if (wave >= N) return;

    const int s = offs[wave];
    const int t = offs[wave + 1];
    float2 acc = make_float2(0.f, 0.f);
    for (int e = s; e < t; ++e) {
        const int   c = bcol[e];
        const float v = bval[e];
        const float2 xv = ((const float2*)(x + (size_t)c * F))[lane];
        acc.x = fmaf(v, xv.x, acc.x);
        acc.y = fmaf(v, xv.y, acc.y);
    }
    ((float2*)(e1 + (size_t)wave * F))[lane] = acc;
}

// ---------------------------------------------------------------------------
// out[i,:] = (x[i,:] - e1[i,:]*(diag+1)) @ W + bias   (in place over e1==out)
// ---------------------------------------------------------------------------
__global__ __launch_bounds__(256) void fused_k(
    const float* __restrict__ x, const float* e1,
    const float* __restrict__ W, const float* __restrict__ diag1,
    const float* __restrict__ bias, float* out, int N)
{
    __shared__ float vs[RB * VSTRIDE];
    const int t  = threadIdx.x;
    const int tx = t & 15;
    const int ty = t >> 4;
    const size_t row0 = (size_t)blockIdx.x * RB;

#pragma unroll
    for (int i = 0; i < 8; ++i) {
        const int idx = t + i * 256;
        const int r   = idx >> 5;
        const int k4  = idx & 31;
        const size_t row = row0 + r;
        float4 v = make_float4(0.f, 0.f, 0.f, 0.f);
        if (row < (size_t)N) {
            const float4 xv = ((const float4*)(x  + row * F))[k4];
            const float4 ev = ((const float4*)(e1 + row * F))[k4];
            const float4 dv = ((const float4*)diag1)[k4];
            v.x = xv.x - ev.x * (dv.x + 1.f);
            v.y = xv.y - ev.y * (dv.y + 1.f);
            v.z = xv.z - ev.z * (dv.z + 1.f);
            v.w = xv.w - ev.w * (dv.w + 1.f);
        }
        *(float4*)&vs[r * VSTRIDE + k4 * 4] = v;
    }
    __syncthreads();

    float acc[4][8];
#pragma unroll
    for (int rr = 0; rr < 4; ++rr)
#pragma unroll
        for (int c = 0; c < 8; ++c) acc[rr][c] = 0.f;

    for (int k = 0; k < F; k += 4) {
        float4 vf[4];
#pragma unroll
        for (int rr = 0; rr < 4; ++rr)
            vf[rr] = *(const float4*)&vs[(ty * 4 + rr) * VSTRIDE + k];
#pragma unroll
        for (int kk = 0; kk < 4; ++kk) {
            const float* wrow = W + (size_t)(k + kk) * F + tx * 8;
            const float4 wa = *(const float4*)(wrow);
            const float4 wb = *(const float4*)(wrow + 4);
#pragma unroll
            for (int rr = 0; rr < 4; ++rr) {
                const float vk = ((const float*)&vf[rr])[kk];
                acc[rr][0] = fmaf(vk, wa.x, acc[rr][0]);
                acc[rr][1] = fmaf(vk, wa.y, acc[rr][1]);
                acc[rr][2] = fmaf(vk, wa.z, acc[rr][2]);
                acc[rr][3] = fmaf(vk, wa.w, acc[rr][3]);
                acc[rr][4] = fmaf(vk, wb.x, acc[rr][4]);
                acc[rr][5] = fmaf(vk, wb.y, acc[rr][5]);
                acc[rr][6] = fmaf(vk, wb.z, acc[rr][6]);
                acc[rr][7] = fmaf(vk, wb.w, acc[rr][7]);
            }
        }
    }

    const float4 b0 = ((const float4*)bias)[tx * 2];
    const float4 b1 = ((const float4*)bias)[tx * 2 + 1];
#pragma unroll
    for (int rr = 0; rr < 4; ++rr) {
        const size_t row = row0 + ty * 4 + rr;
        if (row < (size_t)N) {
            float4 oa = make_float4(acc[rr][0] + b0.x, acc[rr][1] + b0.y,
                                    acc[rr][2] + b0.z, acc[rr][3] + b0.w);
            float4 ob = make_float4(acc[rr][4] + b1.x, acc[rr][5] + b1.y,
                                    acc[rr][6] + b1.z, acc[rr][7] + b1.w);
            ((float4*)(out + row * F))[tx * 2]     = oa;
            ((float4*)(out + row * F))[tx * 2 + 1] = ob;
        }
    }
}

extern "C" void kernel_launch(void* const* d_in, const int* in_sizes, int n_in,
                              void* d_out, int out_size, void* d_ws, size_t ws_size,
                              hipStream_t stream) {
    const float* x        = (const float*)d_in[0];
    const float* edge_val = (const float*)d_in[1];
    const float* weight   = (const float*)d_in[2];
    const float* diag1    = (const float*)d_in[3];
    const float* bias     = (const float*)d_in[4];
    const int*   erow     = (const int*)d_in[5];
    const int*   ecol     = (const int*)d_in[6];
    float* out = (float*)d_out;

    const int E = in_sizes[1];
    const int N = in_sizes[0] / F;

    // Workspace layout (all 4B elements):
    //   offs[N+1] | cnt[N] | cur[N] | bcol[E] | bval[E]
    const size_t need = ((size_t)(3 * N + 1) + 2 * (size_t)E) * 4;

    if (ws_size >= need) {
        int*   offs = (int*)d_ws;
        int*   cnt  = offs + (N + 1);
        int*   cur  = cnt + N;
        int*   bcol = cur + N;
        float* bval = (float*)(bcol + E);

        hipMemsetAsync(cnt, 0, (size_t)N * sizeof(int), stream);
        hipMemsetAsync(cur, 0, (size_t)N * sizeof(int), stream);

        const int eblocks = (E + 255) / 256;
        hist_k <<<eblocks, 256, 0, stream>>>(erow, cnt, E);
        scan_k <<<1, 1024, 0, stream>>>(cnt, offs, N);
        build_k<<<eblocks, 256, 0, stream>>>(erow, ecol, edge_val, offs, cur, bcol, bval, E);

        // e1 lives in d_out; every row written exactly once (zeros if deg 0)
        const int gblocks = (N * 64 + 255) / 256;
        gather_k<<<gblocks, 256, 0, stream>>>(x, bcol, bval, offs, out, N);
    } else {
        // Fallback: atomic scatter path
        hipMemsetAsync(out, 0, (size_t)N * F * sizeof(float), stream);
        scatter_k<<<2048, 256, 0, stream>>>(x, edge_val, erow, ecol, out, E);
    }

    const int fblocks = (N + RB - 1) / RB;
    fused_k<<<fblocks, 256, 0, stream>>>(x, out, weight, diag1, bias, out, N);
}

// Round 5
// 373.753 us; speedup vs baseline: 4.0693x; 1.3775x over previous
//
#include <hip/hip_runtime.h>

#define F 128
#define RB 64
#define VSTRIDE 132
#define SCHUNK 1024   // elements per scan1 block (256 threads x 4)

// ---------------------------------------------------------------------------
// Fallback kernel (only if ws_size too small): edge scatter with f32 atomics
// ---------------------------------------------------------------------------
__global__ __launch_bounds__(256) void scatter_k(
    const float* __restrict__ x, const float* __restrict__ edge_val,
    const int* __restrict__ erow, const int* __restrict__ ecol,
    float* e1, int E)
{
    const int gtid = blockIdx.x * blockDim.x + threadIdx.x;
    const int wid  = gtid >> 6;
    const int nw   = (gridDim.x * blockDim.x) >> 6;
    const int lane = threadIdx.x & 63;
    const int sub  = lane >> 5;
    const int l    = lane & 31;

    for (int e0 = wid * 2; e0 < E; e0 += nw * 2) {
        const int e = e0 + sub;
        if (e < E) {
            const int   r   = erow[e];
            const int   c   = ecol[e];
            const float val = edge_val[e];
            const float4 xv = ((const float4*)(x + (size_t)c * F))[l];
            float* dst = e1 + (size_t)r * F + l * 4;
            unsafeAtomicAdd(dst + 0, val * xv.x);
            unsafeAtomicAdd(dst + 1, val * xv.y);
            unsafeAtomicAdd(dst + 2, val * xv.z);
            unsafeAtomicAdd(dst + 3, val * xv.w);
        }
    }
}

// ---------------------------------------------------------------------------
// CSR build: histogram of destination rows
// ---------------------------------------------------------------------------
__global__ __launch_bounds__(256) void hist_k(
    const int* __restrict__ erow, int* cnt, int E)
{
    int i = blockIdx.x * blockDim.x + threadIdx.x;
    if (i < E) atomicAdd(&cnt[erow[i]], 1);
}

// ---------------------------------------------------------------------------
// Multi-block scan, phase 1: per-block local exclusive scan over SCHUNK elems
// writes local-exclusive offs + per-block total psum[b]
// ---------------------------------------------------------------------------
__global__ __launch_bounds__(256) void scan1_k(
    const int* __restrict__ cnt, int* offs, int* psum, int N)
{
    __shared__ int ts[256];
    const int b = blockIdx.x, t = threadIdx.x;
    const int base = b * SCHUNK + t * 4;
    int v[4];
    int s = 0;
#pragma unroll
    for (int j = 0; j < 4; ++j) {
        v[j] = (base + j < N) ? cnt[base + j] : 0;
        s += v[j];
    }
    ts[t] = s;
    __syncthreads();
    for (int off = 1; off < 256; off <<= 1) {
        int u = (t >= off) ? ts[t - off] : 0;
        __syncthreads();
        ts[t] += u;
        __syncthreads();
    }
    int excl = ts[t] - s;
#pragma unroll
    for (int j = 0; j < 4; ++j) {
        if (base + j < N) offs[base + j] = excl;
        excl += v[j];
    }
    if (t == 255) psum[b] = ts[255];
}

// ---------------------------------------------------------------------------
// Phase 2: single small block scans the NB block sums -> bpref (exclusive),
// writes grand total to offs[N]
// ---------------------------------------------------------------------------
__global__ __launch_bounds__(256) void scan2_k(
    const int* __restrict__ psum, int* bpref, int* offs, int NB, int N)
{
    __shared__ int ts[256];
    const int t = threadIdx.x;
    const int chunk = (NB + 255) >> 8;
    const int begin = t * chunk;
    const int end   = min(begin + chunk, NB);
    int s = 0;
    for (int i = begin; i < end; ++i) s += psum[i];
    ts[t] = s;
    __syncthreads();
    for (int off = 1; off < 256; off <<= 1) {
        int u = (t >= off) ? ts[t - off] : 0;
        __syncthreads();
        ts[t] += u;
        __syncthreads();
    }
    int run = ts[t] - s;
    for (int i = begin; i < end; ++i) { bpref[i] = run; run += psum[i]; }
    if (t == 255) offs[N] = ts[255];
}

// ---------------------------------------------------------------------------
// Phase 3: add block prefix into offs
// ---------------------------------------------------------------------------
__global__ __launch_bounds__(256) void scan3_k(
    int* offs, const int* __restrict__ bpref, int N)
{
    int i = blockIdx.x * blockDim.x + threadIdx.x;
    if (i < N) offs[i] += bpref[i >> 10];   // >>10 == /SCHUNK
}

// ---------------------------------------------------------------------------
// Reorder edges into row buckets: bcol/bval[pos], pos = offs[r] + cursor++
// ---------------------------------------------------------------------------
__global__ __launch_bounds__(256) void build_k(
    const int* __restrict__ erow, const int* __restrict__ ecol,
    const float* __restrict__ eval, const int* __restrict__ offs,
    int* cur, int* bcol, float* bval, int E)
{
    int i = blockIdx.x * blockDim.x + threadIdx.x;
    if (i < E) {
        const int r   = erow[i];
        const int pos = offs[r] + atomicAdd(&cur[r], 1);
        bcol[pos] = ecol[i];
        bval[pos] = eval[i];
    }
}

// ---------------------------------------------------------------------------
// Per-row gather-reduce: e1[r,:] = sum_{e in row r} val_e * x[col_e,:]
// One wave per row; lane handles float2 (64*2 = 128 feats). No atomics.
// ---------------------------------------------------------------------------
__global__ __launch_bounds__(256) void gather_k(
    const float* __restrict__ x, const int* __restrict__ bcol,
    const float* __restrict__ bval, const int* __restrict__ offs,
    float* __restrict__ e1, int N)
{
    const int wave = (blockIdx.x * blockDim.x + threadIdx.x) >> 6;
    const int lane = threadIdx.x & 63;
    if (wave >= N) return;

    const int s = offs[wave];
    const int t = offs[wave + 1];
    float2 acc = make_float2(0.f, 0.f);
    for (int e = s; e < t; ++e) {
        const int   c = bcol[e];
        const float v = bval[e];
        const float2 xv = ((const float2*)(x + (size_t)c * F))[lane];
        acc.x = fmaf(v, xv.x, acc.x);
        acc.y = fmaf(v, xv.y, acc.y);
    }
    ((float2*)(e1 + (size_t)wave * F))[lane] = acc;
}

// ---------------------------------------------------------------------------
// out[i,:] = (x[i,:] - e1[i,:]*(diag+1)) @ W + bias   (in place over e1==out)
// ---------------------------------------------------------------------------
__global__ __launch_bounds__(256) void fused_k(
    const float* __restrict__ x, const float* e1,
    const float* __restrict__ W, const float* __restrict__ diag1,
    const float* __restrict__ bias, float* out, int N)
{
    __shared__ float vs[RB * VSTRIDE];
    const int t  = threadIdx.x;
    const int tx = t & 15;
    const int ty = t >> 4;
    const size_t row0 = (size_t)blockIdx.x * RB;

#pragma unroll
    for (int i = 0; i < 8; ++i) {
        const int idx = t + i * 256;
        const int r   = idx >> 5;
        const int k4  = idx & 31;
        const size_t row = row0 + r;
        float4 v = make_float4(0.f, 0.f, 0.f, 0.f);
        if (row < (size_t)N) {
            const float4 xv = ((const float4*)(x  + row * F))[k4];
            const float4 ev = ((const float4*)(e1 + row * F))[k4];
            const float4 dv = ((const float4*)diag1)[k4];
            v.x = xv.x - ev.x * (dv.x + 1.f);
            v.y = xv.y - ev.y * (dv.y + 1.f);
            v.z = xv.z - ev.z * (dv.z + 1.f);
            v.w = xv.w - ev.w * (dv.w + 1.f);
        }
        *(float4*)&vs[r * VSTRIDE + k4 * 4] = v;
    }
    __syncthreads();

    float acc[4][8];
#pragma unroll
    for (int rr = 0; rr < 4; ++rr)
#pragma unroll
        for (int c = 0; c < 8; ++c) acc[rr][c] = 0.f;

    for (int k = 0; k < F; k += 4) {
        float4 vf[4];
#pragma unroll
        for (int rr = 0; rr < 4; ++rr)
            vf[rr] = *(const float4*)&vs[(ty * 4 + rr) * VSTRIDE + k];
#pragma unroll
        for (int kk = 0; kk < 4; ++kk) {
            const float* wrow = W + (size_t)(k + kk) * F + tx * 8;
            const float4 wa = *(const float4*)(wrow);
            const float4 wb = *(const float4*)(wrow + 4);
#pragma unroll
            for (int rr = 0; rr < 4; ++rr) {
                const float vk = ((const float*)&vf[rr])[kk];
                acc[rr][0] = fmaf(vk, wa.x, acc[rr][0]);
                acc[rr][1] = fmaf(vk, wa.y, acc[rr][1]);
                acc[rr][2] = fmaf(vk, wa.z, acc[rr][2]);
                acc[rr][3] = fmaf(vk, wa.w, acc[rr][3]);
                acc[rr][4] = fmaf(vk, wb.x, acc[rr][4]);
                acc[rr][5] = fmaf(vk, wb.y, acc[rr][5]);
                acc[rr][6] = fmaf(vk, wb.z, acc[rr][6]);
                acc[rr][7] = fmaf(vk, wb.w, acc[rr][7]);
            }
        }
    }

    const float4 b0 = ((const float4*)bias)[tx * 2];
    const float4 b1 = ((const float4*)bias)[tx * 2 + 1];
#pragma unroll
    for (int rr = 0; rr < 4; ++rr) {
        const size_t row = row0 + ty * 4 + rr;
        if (row < (size_t)N) {
            float4 oa = make_float4(acc[rr][0] + b0.x, acc[rr][1] + b0.y,
                                    acc[rr][2] + b0.z, acc[rr][3] + b0.w);
            float4 ob = make_float4(acc[rr][4] + b1.x, acc[rr][5] + b1.y,
                                    acc[rr][6] + b1.z, acc[rr][7] + b1.w);
            ((float4*)(out + row * F))[tx * 2]     = oa;
            ((float4*)(out + row * F))[tx * 2 + 1] = ob;
        }
    }
}

extern "C" void kernel_launch(void* const* d_in, const int* in_sizes, int n_in,
                              void* d_out, int out_size, void* d_ws, size_t ws_size,
                              hipStream_t stream) {
    const float* x        = (const float*)d_in[0];
    const float* edge_val = (const float*)d_in[1];
    const float* weight   = (const float*)d_in[2];
    const float* diag1    = (const float*)d_in[3];
    const float* bias     = (const float*)d_in[4];
    const int*   erow     = (const int*)d_in[5];
    const int*   ecol     = (const int*)d_in[6];
    float* out = (float*)d_out;

    const int E  = in_sizes[1];
    const int N  = in_sizes[0] / F;
    const int NB = (N + SCHUNK - 1) / SCHUNK;   // scan blocks

    // Workspace layout (4B elems):
    //   offs[N+1] | cnt[N] | cur[N] | psum[NB] | bpref[NB] | bcol[E] | bval[E]
    const size_t need = ((size_t)(3 * N + 1) + 2 * (size_t)NB + 2 * (size_t)E) * 4;

    if (ws_size >= need) {
        int*   offs  = (int*)d_ws;
        int*   cnt   = offs + (N + 1);
        int*   cur   = cnt + N;
        int*   psum  = cur + N;
        int*   bpref = psum + NB;
        int*   bcol  = bpref + NB;
        float* bval  = (float*)(bcol + E);

        // cnt and cur are adjacent -> one memset
        hipMemsetAsync(cnt, 0, (size_t)(2 * N) * sizeof(int), stream);

        const int eblocks = (E + 255) / 256;
        hist_k <<<eblocks, 256, 0, stream>>>(erow, cnt, E);
        scan1_k<<<NB, 256, 0, stream>>>(cnt, offs, psum, N);
        scan2_k<<<1, 256, 0, stream>>>(psum, bpref, offs, NB, N);
        scan3_k<<<(N + 255) / 256, 256, 0, stream>>>(offs, bpref, N);
        build_k<<<eblocks, 256, 0, stream>>>(erow, ecol, edge_val, offs, cur, bcol, bval, E);

        // e1 lives in d_out; every row written exactly once (zeros if deg 0)
        const int gblocks = (N * 64 + 255) / 256;
        gather_k<<<gblocks, 256, 0, stream>>>(x, bcol, bval, offs, out, N);
    } else {
        // Fallback: atomic scatter path
        hipMemsetAsync(out, 0, (size_t)N * F * sizeof(float), stream);
        scatter_k<<<2048, 256, 0, stream>>>(x, edge_val, erow, ecol, out, E);
    }

    const int fblocks = (N + RB - 1) / RB;
    fused_k<<<fblocks, 256, 0, stream>>>(x, out, weight, diag1, bias, out, N);
}

// Round 8
// 335.754 us; speedup vs baseline: 4.5298x; 1.1132x over previous
//
#include <hip/hip_runtime.h>

#define F 128
#define BM 128        // fused_k rows per block
#define VS 132        // LDS row stride (floats): 16B-aligned, ty-stride = 4 banks
#define SCHUNK 1024   // elements per scan1 block (256 threads x 4)

// ---------------------------------------------------------------------------
// Fallback kernel (only if ws_size too small): edge scatter with f32 atomics
// ---------------------------------------------------------------------------
__global__ __launch_bounds__(256) void scatter_k(
    const float* __restrict__ x, const float* __restrict__ edge_val,
    const int* __restrict__ erow, const int* __restrict__ ecol,
    float* e1, int E)
{
    const int gtid = blockIdx.x * blockDim.x + threadIdx.x;
    const int wid  = gtid >> 6;
    const int nw   = (gridDim.x * blockDim.x) >> 6;
    const int lane = threadIdx.x & 63;
    const int sub  = lane >> 5;
    const int l    = lane & 31;

    for (int e0 = wid * 2; e0 < E; e0 += nw * 2) {
        const int e = e0 + sub;
        if (e < E) {
            const int   r   = erow[e];
            const int   c   = ecol[e];
            const float val = edge_val[e];
            const float4 xv = ((const float4*)(x + (size_t)c * F))[l];
            float* dst = e1 + (size_t)r * F + l * 4;
            unsafeAtomicAdd(dst + 0, val * xv.x);
            unsafeAtomicAdd(dst + 1, val * xv.y);
            unsafeAtomicAdd(dst + 2, val * xv.z);
            unsafeAtomicAdd(dst + 3, val * xv.w);
        }
    }
}

// ---------------------------------------------------------------------------
// CSR build: histogram of destination rows
// ---------------------------------------------------------------------------
__global__ __launch_bounds__(256) void hist_k(
    const int* __restrict__ erow, int* cnt, int E)
{
    int i = blockIdx.x * blockDim.x + threadIdx.x;
    if (i < E) atomicAdd(&cnt[erow[i]], 1);
}

// ---------------------------------------------------------------------------
// Multi-block scan, phase 1: per-block local exclusive scan over SCHUNK elems
// ---------------------------------------------------------------------------
__global__ __launch_bounds__(256) void scan1_k(
    const int* __restrict__ cnt, int* offs, int* psum, int N)
{
    __shared__ int ts[256];
    const int b = blockIdx.x, t = threadIdx.x;
    const int base = b * SCHUNK + t * 4;
    int v[4];
    int s = 0;
#pragma unroll
    for (int j = 0; j < 4; ++j) {
        v[j] = (base + j < N) ? cnt[base + j] : 0;
        s += v[j];
    }
    ts[t] = s;
    __syncthreads();
    for (int off = 1; off < 256; off <<= 1) {
        int u = (t >= off) ? ts[t - off] : 0;
        __syncthreads();
        ts[t] += u;
        __syncthreads();
    }
    int excl = ts[t] - s;
#pragma unroll
    for (int j = 0; j < 4; ++j) {
        if (base + j < N) offs[base + j] = excl;
        excl += v[j];
    }
    if (t == 255) psum[b] = ts[255];
}

// ---------------------------------------------------------------------------
// Phase 2: single small block scans the NB block sums -> bpref (exclusive)
// ---------------------------------------------------------------------------
__global__ __launch_bounds__(256) void scan2_k(
    const int* __restrict__ psum, int* bpref, int* offs, int NB, int N)
{
    __shared__ int ts[256];
    const int t = threadIdx.x;
    const int chunk = (NB + 255) >> 8;
    const int begin = t * chunk;
    const int end   = min(begin + chunk, NB);
    int s = 0;
    for (int i = begin; i < end; ++i) s += psum[i];
    ts[t] = s;
    __syncthreads();
    for (int off = 1; off < 256; off <<= 1) {
        int u = (t >= off) ? ts[t - off] : 0;
        __syncthreads();
        ts[t] += u;
        __syncthreads();
    }
    int run = ts[t] - s;
    for (int i = begin; i < end; ++i) { bpref[i] = run; run += psum[i]; }
    if (t == 255) offs[N] = ts[255];
}

// ---------------------------------------------------------------------------
// Phase 3: add block prefix into offs
// ---------------------------------------------------------------------------
__global__ __launch_bounds__(256) void scan3_k(
    int* offs, const int* __restrict__ bpref, int N)
{
    int i = blockIdx.x * blockDim.x + threadIdx.x;
    if (i < N) offs[i] += bpref[i >> 10];   // >>10 == /SCHUNK
}

// ---------------------------------------------------------------------------
// Reorder edges into row buckets
// ---------------------------------------------------------------------------
__global__ __launch_bounds__(256) void build_k(
    const int* __restrict__ erow, const int* __restrict__ ecol,
    const float* __restrict__ eval, const int* __restrict__ offs,
    int* cur, int* bcol, float* bval, int E)
{
    int i = blockIdx.x * blockDim.x + threadIdx.x;
    if (i < E) {
        const int r   = erow[i];
        const int pos = offs[r] + atomicAdd(&cur[r], 1);
        bcol[pos] = ecol[i];
        bval[pos] = eval[i];
    }
}

// ---------------------------------------------------------------------------
// Per-row gather-reduce, 4-way unrolled for ILP: break the per-edge
// dependent-load chain (meta load -> x gather) into 4 independent streams.
// One wave per row; lane handles float2. No atomics.
// ---------------------------------------------------------------------------
__global__ __launch_bounds__(256) void gather_k(
    const float* __restrict__ x, const int* __restrict__ bcol,
    const float* __restrict__ bval, const int* __restrict__ offs,
    float* __restrict__ e1, int N)
{
    const int wave = (blockIdx.x * blockDim.x + threadIdx.x) >> 6;
    const int lane = threadIdx.x & 63;
    if (wave >= N) return;

    const int s = offs[wave];
    const int t = offs[wave + 1];
    float2 acc = make_float2(0.f, 0.f);
    int e = s;
    for (; e + 4 <= t; e += 4) {
        const int   c0 = bcol[e + 0], c1 = bcol[e + 1];
        const int   c2 = bcol[e + 2], c3 = bcol[e + 3];
        const float v0 = bval[e + 0], v1 = bval[e + 1];
        const float v2 = bval[e + 2], v3 = bval[e + 3];
        const float2 a0 = ((const float2*)(x + (size_t)c0 * F))[lane];
        const float2 a1 = ((const float2*)(x + (size_t)c1 * F))[lane];
        const float2 a2 = ((const float2*)(x + (size_t)c2 * F))[lane];
        const float2 a3 = ((const float2*)(x + (size_t)c3 * F))[lane];
        acc.x = fmaf(v0, a0.x, acc.x); acc.y = fmaf(v0, a0.y, acc.y);
        acc.x = fmaf(v1, a1.x, acc.x); acc.y = fmaf(v1, a1.y, acc.y);
        acc.x = fmaf(v2, a2.x, acc.x); acc.y = fmaf(v2, a2.y, acc.y);
        acc.x = fmaf(v3, a3.x, acc.x); acc.y = fmaf(v3, a3.y, acc.y);
    }
    for (; e < t; ++e) {
        const int   c = bcol[e];
        const float v = bval[e];
        const float2 xv = ((const float2*)(x + (size_t)c * F))[lane];
        acc.x = fmaf(v, xv.x, acc.x);
        acc.y = fmaf(v, xv.y, acc.y);
    }
    ((float2*)(e1 + (size_t)wave * F))[lane] = acc;
}

// ---------------------------------------------------------------------------
// out[i,:] = (x[i,:] - e1[i,:]*(diag+1)) @ W + bias   (in place over e1==out)
// Block: 256 threads = 16(tx) x 16(ty); thread tile: 8 rows x 8 cols.
// Rows assigned STRIDED (row = ty + rr*16) so the 4 ty-groups of a wave read
// LDS addrs 132 words apart (4 distinct banks) -> conflict-free broadcasts.
// ---------------------------------------------------------------------------
__global__ __launch_bounds__(256) void fused_k(
    const float* __restrict__ x, const float* e1,
    const float* __restrict__ W, const float* __restrict__ diag1,
    const float* __restrict__ bias, float* out, int N)
{
    __shared__ float vs[BM * VS];   // 128*132*4 = 67.6 KB
    const int t  = threadIdx.x;
    const int tx = t & 15;          // output cols tx*8 .. tx*8+7
    const int ty = t >> 4;          // base row; thread rows = ty + rr*16
    const size_t row0 = (size_t)blockIdx.x * BM;

    // Phase 1: stage v = x - e1*(diag+1) for BM rows (4096 float4 chunks)
#pragma unroll
    for (int i = 0; i < 16; ++i) {
        const int idx = t + i * 256;
        const int r   = idx >> 5;
        const int k4  = idx & 31;
        const size_t row = row0 + r;
        float4 v = make_float4(0.f, 0.f, 0.f, 0.f);
        if (row < (size_t)N) {
            const float4 xv = ((const float4*)(x  + row * F))[k4];
            const float4 ev = ((const float4*)(e1 + row * F))[k4];
            const float4 dv = ((const float4*)diag1)[k4];
            v.x = xv.x - ev.x * (dv.x + 1.f);
            v.y = xv.y - ev.y * (dv.y + 1.f);
            v.z = xv.z - ev.z * (dv.z + 1.f);
            v.w = xv.w - ev.w * (dv.w + 1.f);
        }
        *(float4*)&vs[r * VS + k4 * 4] = v;
    }
    __syncthreads();

    float acc[8][8];
#pragma unroll
    for (int rr = 0; rr < 8; ++rr)
#pragma unroll
        for (int c = 0; c < 8; ++c) acc[rr][c] = 0.f;

    for (int k = 0; k < F; k += 4) {
        float4 vf[8];
#pragma unroll
        for (int rr = 0; rr < 8; ++rr)
            vf[rr] = *(const float4*)&vs[(ty + rr * 16) * VS + k];
#pragma unroll
        for (int kk = 0; kk < 4; ++kk) {
            const float* wrow = W + (size_t)(k + kk) * F + tx * 8;
            const float4 wa = *(const float4*)(wrow);
            const float4 wb = *(const float4*)(wrow + 4);
#pragma unroll
            for (int rr = 0; rr < 8; ++rr) {
                const float vk = ((const float*)&vf[rr])[kk];
                acc[rr][0] = fmaf(vk, wa.x, acc[rr][0]);
                acc[rr][1] = fmaf(vk, wa.y, acc[rr][1]);
                acc[rr][2] = fmaf(vk, wa.z, acc[rr][2]);
                acc[rr][3] = fmaf(vk, wa.w, acc[rr][3]);
                acc[rr][4] = fmaf(vk, wb.x, acc[rr][4]);
                acc[rr][5] = fmaf(vk, wb.y, acc[rr][5]);
                acc[rr][6] = fmaf(vk, wb.z, acc[rr][6]);
                acc[rr][7] = fmaf(vk, wb.w, acc[rr][7]);
            }
        }
    }

    const float4 b0 = *(const float4*)(bias + tx * 8);
    const float4 b1 = *(const float4*)(bias + tx * 8 + 4);
#pragma unroll
    for (int rr = 0; rr < 8; ++rr) {
        const size_t row = row0 + ty + rr * 16;
        if (row < (size_t)N) {
            float4 oa = make_float4(acc[rr][0] + b0.x, acc[rr][1] + b0.y,
                                    acc[rr][2] + b0.z, acc[rr][3] + b0.w);
            float4 ob = make_float4(acc[rr][4] + b1.x, acc[rr][5] + b1.y,
                                    acc[rr][6] + b1.z, acc[rr][7] + b1.w);
            ((float4*)(out + row * F))[tx * 2]     = oa;
            ((float4*)(out + row * F))[tx * 2 + 1] = ob;
        }
    }
}

extern "C" void kernel_launch(void* const* d_in, const int* in_sizes, int n_in,
                              void* d_out, int out_size, void* d_ws, size_t ws_size,
                              hipStream_t stream) {
    const float* x        = (const float*)d_in[0];
    const float* edge_val = (const float*)d_in[1];
    const float* weight   = (const float*)d_in[2];
    const float* diag1    = (const float*)d_in[3];
    const float* bias     = (const float*)d_in[4];
    const int*   erow     = (const int*)d_in[5];
    const int*   ecol     = (const int*)d_in[6];
    float* out = (float*)d_out;

    const int E  = in_sizes[1];
    const int N  = in_sizes[0] / F;
    const int NB = (N + SCHUNK - 1) / SCHUNK;   // scan blocks

    // Workspace layout (4B elems):
    //   offs[N+1] | cnt[N] | cur[N] | psum[NB] | bpref[NB] | bcol[E] | bval[E]
    const size_t need = ((size_t)(3 * N + 1) + 2 * (size_t)NB + 2 * (size_t)E) * 4;

    if (ws_size >= need) {
        int*   offs  = (int*)d_ws;
        int*   cnt   = offs + (N + 1);
        int*   cur   = cnt + N;
        int*   psum  = cur + N;
        int*   bpref = psum + NB;
        int*   bcol  = bpref + NB;
        float* bval  = (float*)(bcol + E);

        // cnt and cur are adjacent -> one memset
        hipMemsetAsync(cnt, 0, (size_t)(2 * N) * sizeof(int), stream);

        const int eblocks = (E + 255) / 256;
        hist_k <<<eblocks, 256, 0, stream>>>(erow, cnt, E);
        scan1_k<<<NB, 256, 0, stream>>>(cnt, offs, psum, N);
        scan2_k<<<1, 256, 0, stream>>>(psum, bpref, offs, NB, N);
        scan3_k<<<(N + 255) / 256, 256, 0, stream>>>(offs, bpref, N);
        build_k<<<eblocks, 256, 0, stream>>>(erow, ecol, edge_val, offs, cur, bcol, bval, E);

        // e1 lives in d_out; every row written exactly once (zeros if deg 0)
        const int gblocks = (N * 64 + 255) / 256;
        gather_k<<<gblocks, 256, 0, stream>>>(x, bcol, bval, offs, out, N);
    } else {
        // Fallback: atomic scatter path
        hipMemsetAsync(out, 0, (size_t)N * F * sizeof(float), stream);
        scatter_k<<<2048, 256, 0, stream>>>(x, edge_val, erow, ecol, out, E);
    }

    const int fblocks = (N + BM - 1) / BM;
    fused_k<<<fblocks, 256, 0, stream>>>(x, out, weight, diag1, bias, out, N);
}

// Round 10
// 325.200 us; speedup vs baseline: 4.6768x; 1.0325x over previous
//
#include <hip/hip_runtime.h>

#define F 128
#define BM 64         // fused_k rows per block (LDS 33.8 KB -> 4 blocks/CU)
#define VS 132        // LDS row stride (floats): 16B-aligned, ty-stride = 4 banks
#define SCHUNK 1024   // elements per scan1 block (256 threads x 4)

// ---------------------------------------------------------------------------
// Fallback kernels (only if ws_size too small): atomic scatter + v-build
// ---------------------------------------------------------------------------
__global__ __launch_bounds__(256) void scatter_k(
    const float* __restrict__ x, const float* __restrict__ edge_val,
    const int* __restrict__ erow, const int* __restrict__ ecol,
    float* e1, int E)
{
    const int gtid = blockIdx.x * blockDim.x + threadIdx.x;
    const int wid  = gtid >> 6;
    const int nw   = (gridDim.x * blockDim.x) >> 6;
    const int lane = threadIdx.x & 63;
    const int sub  = lane >> 5;
    const int l    = lane & 31;

    for (int e0 = wid * 2; e0 < E; e0 += nw * 2) {
        const int e = e0 + sub;
        if (e < E) {
            const int   r   = erow[e];
            const int   c   = ecol[e];
            const float val = edge_val[e];
            const float4 xv = ((const float4*)(x + (size_t)c * F))[l];
            float* dst = e1 + (size_t)r * F + l * 4;
            unsafeAtomicAdd(dst + 0, val * xv.x);
            unsafeAtomicAdd(dst + 1, val * xv.y);
            unsafeAtomicAdd(dst + 2, val * xv.z);
            unsafeAtomicAdd(dst + 3, val * xv.w);
        }
    }
}

__global__ __launch_bounds__(256) void mkv_k(
    const float* __restrict__ x, const float* __restrict__ diag1,
    float* v, int n4)   // n4 = N*F/4; v holds e1 in, v out
{
    int i = blockIdx.x * blockDim.x + threadIdx.x;
    if (i < n4) {
        const float4 xv = ((const float4*)x)[i];
        const float4 ev = ((const float4*)v)[i];
        const float4 dv = ((const float4*)diag1)[i & 31];
        float4 o;
        o.x = xv.x - ev.x * (dv.x + 1.f);
        o.y = xv.y - ev.y * (dv.y + 1.f);
        o.z = xv.z - ev.z * (dv.z + 1.f);
        o.w = xv.w - ev.w * (dv.w + 1.f);
        ((float4*)v)[i] = o;
    }
}

// ---------------------------------------------------------------------------
// CSR build: histogram of destination rows
// ---------------------------------------------------------------------------
__global__ __launch_bounds__(256) void hist_k(
    const int* __restrict__ erow, int* cnt, int E)
{
    int i = blockIdx.x * blockDim.x + threadIdx.x;
    if (i < E) atomicAdd(&cnt[erow[i]], 1);
}

// ---------------------------------------------------------------------------
// Multi-block scan, phase 1: per-block local exclusive scan over SCHUNK elems
// ---------------------------------------------------------------------------
__global__ __launch_bounds__(256) void scan1_k(
    const int* __restrict__ cnt, int* offs, int* psum, int N)
{
    __shared__ int ts[256];
    const int b = blockIdx.x, t = threadIdx.x;
    const int base = b * SCHUNK + t * 4;
    int v[4];
    int s = 0;
#pragma unroll
    for (int j = 0; j < 4; ++j) {
        v[j] = (base + j < N) ? cnt[base + j] : 0;
        s += v[j];
    }
    ts[t] = s;
    __syncthreads();
    for (int off = 1; off < 256; off <<= 1) {
        int u = (t >= off) ? ts[t - off] : 0;
        __syncthreads();
        ts[t] += u;
        __syncthreads();
    }
    int excl = ts[t] - s;
#pragma unroll
    for (int j = 0; j < 4; ++j) {
        if (base + j < N) offs[base + j] = excl;
        excl += v[j];
    }
    if (t == 255) psum[b] = ts[255];
}

// ---------------------------------------------------------------------------
// Phase 2: single small block scans the NB block sums -> bpref (exclusive)
// ---------------------------------------------------------------------------
__global__ __launch_bounds__(256) void scan2_k(
    const int* __restrict__ psum, int* bpref, int* offs, int NB, int N)
{
    __shared__ int ts[256];
    const int t = threadIdx.x;
    const int chunk = (NB + 255) >> 8;
    const int begin = t * chunk;
    const int end   = min(begin + chunk, NB);
    int s = 0;
    for (int i = begin; i < end; ++i) s += psum[i];
    ts[t] = s;
    __syncthreads();
    for (int off = 1; off < 256; off <<= 1) {
        int u = (t >= off) ? ts[t - off] : 0;
        __syncthreads();
        ts[t] += u;
        __syncthreads();
    }
    int run = ts[t] - s;
    for (int i = begin; i < end; ++i) { bpref[i] = run; run += psum[i]; }
    if (t == 255) offs[N] = ts[255];
}

// ---------------------------------------------------------------------------
// Phase 3: add block prefix into offs
// ---------------------------------------------------------------------------
__global__ __launch_bounds__(256) void scan3_k(
    int* offs, const int* __restrict__ bpref, int N)
{
    int i = blockIdx.x * blockDim.x + threadIdx.x;
    if (i < N) offs[i] += bpref[i >> 10];   // >>10 == /SCHUNK
}

// ---------------------------------------------------------------------------
// Reorder edges into row buckets
// ---------------------------------------------------------------------------
__global__ __launch_bounds__(256) void build_k(
    const int* __restrict__ erow, const int* __restrict__ ecol,
    const float* __restrict__ eval, const int* __restrict__ offs,
    int* cur, int* bcol, float* bval, int E)
{
    int i = blockIdx.x * blockDim.x + threadIdx.x;
    if (i < E) {
        const int r   = erow[i];
        const int pos = offs[r] + atomicAdd(&cur[r], 1);
        bcol[pos] = ecol[i];
        bval[pos] = eval[i];
    }
}

// ---------------------------------------------------------------------------
// Per-row gather-reduce + v finalize:
//   v[r,:] = x[r,:] - (sum_e val_e * x[col_e,:]) * (diag+1)
// One wave per row; lane handles float2. 4-way edge unroll for ILP.
// Writes v (the GEMM A-operand) directly -> fused_k never touches x/e1/diag.
// ---------------------------------------------------------------------------
__global__ __launch_bounds__(256) void gatherv_k(
    const float* __restrict__ x, const int* __restrict__ bcol,
    const float* __restrict__ bval, const int* __restrict__ offs,
    const float* __restrict__ diag1, float* __restrict__ vout, int N)
{
    const int wave = (blockIdx.x * blockDim.x + threadIdx.x) >> 6;
    const int lane = threadIdx.x & 63;
    if (wave >= N) return;

    const int s = offs[wave];
    const int t = offs[wave + 1];
    // issue the own-row and diag loads early; consumed after the edge loop
    const float2 xr = ((const float2*)(x + (size_t)wave * F))[lane];
    const float2 dv = ((const float2*)diag1)[lane];

    float2 acc = make_float2(0.f, 0.f);
    int e = s;
    for (; e + 4 <= t; e += 4) {
        const int   c0 = bcol[e + 0], c1 = bcol[e + 1];
        const int   c2 = bcol[e + 2], c3 = bcol[e + 3];
        const float v0 = bval[e + 0], v1 = bval[e + 1];
        const float v2 = bval[e + 2], v3 = bval[e + 3];
        const float2 a0 = ((const float2*)(x + (size_t)c0 * F))[lane];
        const float2 a1 = ((const float2*)(x + (size_t)c1 * F))[lane];
        const float2 a2 = ((const float2*)(x + (size_t)c2 * F))[lane];
        const float2 a3 = ((const float2*)(x + (size_t)c3 * F))[lane];
        acc.x = fmaf(v0, a0.x, acc.x); acc.y = fmaf(v0, a0.y, acc.y);
        acc.x = fmaf(v1, a1.x, acc.x); acc.y = fmaf(v1, a1.y, acc.y);
        acc.x = fmaf(v2, a2.x, acc.x); acc.y = fmaf(v2, a2.y, acc.y);
        acc.x = fmaf(v3, a3.x, acc.x); acc.y = fmaf(v3, a3.y, acc.y);
    }
    for (; e < t; ++e) {
        const int   c = bcol[e];
        const float v = bval[e];
        const float2 xv = ((const float2*)(x + (size_t)c * F))[lane];
        acc.x = fmaf(v, xv.x, acc.x);
        acc.y = fmaf(v, xv.y, acc.y);
    }
    float2 v;
    v.x = xr.x - acc.x * (dv.x + 1.f);
    v.y = xr.y - acc.y * (dv.y + 1.f);
    ((float2*)(vout + (size_t)wave * F))[lane] = v;
}

// ---------------------------------------------------------------------------
// out[i,:] = v[i,:] @ W + bias   (in place: v == out)
// Block: 256 threads = 16(tx) x 16(ty); thread tile: 4 rows x 8 cols.
// BM=64 -> LDS 33.8 KB -> 4 blocks/CU (16 waves, 50% occupancy cap).
// Rows STRIDED (row = ty + rr*16): 4 ty-groups/wave read LDS addrs 132 words
// apart (4 distinct banks) -> conflict-free broadcasts.
// ---------------------------------------------------------------------------
__global__ __launch_bounds__(256) void fused_k(
    const float* v, const float* __restrict__ W,
    const float* __restrict__ bias, float* out, int N)
{
    __shared__ float vs[BM * VS];   // 64*132*4 = 33.8 KB
    const int t  = threadIdx.x;
    const int tx = t & 15;          // output cols tx*8 .. tx*8+7
    const int ty = t >> 4;          // base row; thread rows = ty + rr*16
    const size_t row0 = (size_t)blockIdx.x * BM;

    // Phase 1: stage v tile (pure copy; 2048 float4 chunks)
#pragma unroll
    for (int i = 0; i < 8; ++i) {
        const int idx = t + i * 256;
        const int r   = idx >> 5;
        const int k4  = idx & 31;
        const size_t row = row0 + r;
        float4 val = make_float4(0.f, 0.f, 0.f, 0.f);
        if (row < (size_t)N)
            val = ((const float4*)(v + row * F))[k4];
        *(float4*)&vs[r * VS + k4 * 4] = val;
    }
    __syncthreads();

    float acc[4][8];
#pragma unroll
    for (int rr = 0; rr < 4; ++rr)
#pragma unroll
        for (int c = 0; c < 8; ++c) acc[rr][c] = 0.f;

    for (int k = 0; k < F; k += 4) {
        float4 vf[4];
#pragma unroll
        for (int rr = 0; rr < 4; ++rr)
            vf[rr] = *(const float4*)&vs[(ty + rr * 16) * VS + k];
#pragma unroll
        for (int kk = 0; kk < 4; ++kk) {
            const float* wrow = W + (size_t)(k + kk) * F + tx * 8;
            const float4 wa = *(const float4*)(wrow);
            const float4 wb = *(const float4*)(wrow + 4);
#pragma unroll
            for (int rr = 0; rr < 4; ++rr) {
                const float vk = ((const float*)&vf[rr])[kk];
                acc[rr][0] = fmaf(vk, wa.x, acc[rr][0]);
                acc[rr][1] = fmaf(vk, wa.y, acc[rr][1]);
                acc[rr][2] = fmaf(vk, wa.z, acc[rr][2]);
                acc[rr][3] = fmaf(vk, wa.w, acc[rr][3]);
                acc[rr][4] = fmaf(vk, wb.x, acc[rr][4]);
                acc[rr][5] = fmaf(vk, wb.y, acc[rr][5]);
                acc[rr][6] = fmaf(vk, wb.z, acc[rr][6]);
                acc[rr][7] = fmaf(vk, wb.w, acc[rr][7]);
            }
        }
    }

    const float4 b0 = *(const float4*)(bias + tx * 8);
    const float4 b1 = *(const float4*)(bias + tx * 8 + 4);
#pragma unroll
    for (int rr = 0; rr < 4; ++rr) {
        const size_t row = row0 + ty + rr * 16;
        if (row < (size_t)N) {
            float4 oa = make_float4(acc[rr][0] + b0.x, acc[rr][1] + b0.y,
                                    acc[rr][2] + b0.z, acc[rr][3] + b0.w);
            float4 ob = make_float4(acc[rr][4] + b1.x, acc[rr][5] + b1.y,
                                    acc[rr][6] + b1.z, acc[rr][7] + b1.w);
            ((float4*)(out + row * F))[tx * 2]     = oa;
            ((float4*)(out + row * F))[tx * 2 + 1] = ob;
        }
    }
}

extern "C" void kernel_launch(void* const* d_in, const int* in_sizes, int n_in,
                              void* d_out, int out_size, void* d_ws, size_t ws_size,
                              hipStream_t stream) {
    const float* x        = (const float*)d_in[0];
    const float* edge_val = (const float*)d_in[1];
    const float* weight   = (const float*)d_in[2];
    const float* diag1    = (const float*)d_in[3];
    const float* bias     = (const float*)d_in[4];
    const int*   erow     = (const int*)d_in[5];
    const int*   ecol     = (const int*)d_in[6];
    float* out = (float*)d_out;

    const int E  = in_sizes[1];
    const int N  = in_sizes[0] / F;
    const int NB = (N + SCHUNK - 1) / SCHUNK;   // scan blocks

    // Workspace layout (4B elems):
    //   offs[N+1] | cnt[N] | cur[N] | psum[NB] | bpref[NB] | bcol[E] | bval[E]
    const size_t need = ((size_t)(3 * N + 1) + 2 * (size_t)NB + 2 * (size_t)E) * 4;

    if (ws_size >= need) {
        int*   offs  = (int*)d_ws;
        int*   cnt   = offs + (N + 1);
        int*   cur   = cnt + N;
        int*   psum  = cur + N;
        int*   bpref = psum + NB;
        int*   bcol  = bpref + NB;
        float* bval  = (float*)(bcol + E);

        hipMemsetAsync(cnt, 0, (size_t)(2 * N) * sizeof(int), stream);

        const int eblocks = (E + 255) / 256;
        hist_k <<<eblocks, 256, 0, stream>>>(erow, cnt, E);
        scan1_k<<<NB, 256, 0, stream>>>(cnt, offs, psum, N);
        scan2_k<<<1, 256, 0, stream>>>(psum, bpref, offs, NB, N);
        scan3_k<<<(N + 255) / 256, 256, 0, stream>>>(offs, bpref, N);
        build_k<<<eblocks, 256, 0, stream>>>(erow, ecol, edge_val, offs, cur, bcol, bval, E);

        // v lives in d_out; every row written exactly once (deg-0 -> v = x)
        const int gblocks = (N * 64 + 255) / 256;
        gatherv_k<<<gblocks, 256, 0, stream>>>(x, bcol, bval, offs, diag1, out, N);
    } else {
        // Fallback: atomic scatter + separate v-build
        hipMemsetAsync(out, 0, (size_t)N * F * sizeof(float), stream);
        scatter_k<<<2048, 256, 0, stream>>>(x, edge_val, erow, ecol, out, E);
        const int n4 = N * F / 4;
        mkv_k<<<(n4 + 255) / 256, 256, 0, stream>>>(x, diag1, out, n4);
    }

    const int fblocks = (N + BM - 1) / BM;
    fused_k<<<fblocks, 256, 0, stream>>>(out, weight, bias, out, N);
}